// Round 6
// baseline (547.027 us; speedup 1.0000x reference)
//
#include <hip/hip_runtime.h>
#include <cstddef>

typedef unsigned short ushort_t;
typedef __attribute__((ext_vector_type(8))) short bf16x8;
typedef __attribute__((ext_vector_type(4))) float f32x4;
typedef __attribute__((ext_vector_type(16))) float f32x16;

// ---------------- workspace layout (float offsets) ----------------
// [0..1048576): p0 (4096x256) -> dots (1024x1024); obk (packed bf16 6144x128 =
//               393216 f) at +524288 once dots is dead (after argmin).
#define WS_P0     0u
#define WS_DOTS   0u
#define WS_OBK    524288u
#define WS_HN0    1048576u   /* 4096x256; -> bitmap (524288 words) after h1 gemm; -> hc after fused */
#define WS_BITMAP 1048576u
#define WS_HC     1048576u
#define WS_H1     2097152u   /* 4096x128 */
#define WS_H1N    2621440u   /* 4096x128 */
#define WS_P1     3145728u   /* 4096x128; -> pvb (bf16 packed 192 tiles = 393216 f) */
#define WS_PVB    3145728u
#define WS_HN1    3670016u   /* 4096x128 */
#define WS_H2     4194304u   /* 4096x128 (live to the end now) */
#define WS_X      4718592u   /* synth 2048x128 (rows >= 4096 of x) */
#define WS_OB     5505024u   /* (unused now) */
// ---- contiguous zero region (one memset): ----
#define WS_NEIGH  6291456u   /* 786432 */
#define WS_ROWSUM 7077888u   /* 6144 */
#define WS_SCAL   7084032u   /* 16 floats: [S_all, s1, -, sub, ecount_f] */
#define WS_DEG    7084048u   /* int 4096 */
// ---- end zero region ----
#define WS_NN     7088144u   /* int 1024 */
#define WS_CUR    7089168u   /* int 4096 */
#define WS_ROWPTR 7093264u   /* int 4097 */
#define WS_EIDX   7097361u   /* int 69632 */

__device__ inline ushort_t f2bf(float f) {
  unsigned u = __float_as_uint(f);
  u += 0x7fff + ((u >> 16) & 1);   // round-to-nearest-even
  return (ushort_t)(u >> 16);
}

// ---------------- generic NT GEMM: C = act(A@B^T (+ A2@B2^T) + bias) -------
// Ahi: optional second A base for rows >= 4096 (split h2/synth, block-uniform).
// Cb: when set, write bf16 output in the obk-packed fragment layout.
__global__ __launch_bounds__(256, 2) void gemm_nt(
    const float* __restrict__ A, int lda,
    const float* __restrict__ B, int ldb,
    const float* __restrict__ A2, int lda2,
    const float* __restrict__ B2, int ldb2,
    const float* __restrict__ bias,
    float* __restrict__ C, int ldc,
    int K, int relu,
    ushort_t* __restrict__ Cb,
    const float* __restrict__ a2scale,
    const float* __restrict__ Ahi)
{
  __shared__ float As[16][68];
  __shared__ float Bs[16][68];
  const int tid = threadIdx.x;
  const int tx = tid & 15, ty = tid >> 4;
  const int lr = tid >> 2;
  const int lk = (tid & 3) << 2;
  const int i0 = blockIdx.y << 6;
  const int j0 = blockIdx.x << 6;
  float acc[4][4] = {};
  const int npass = (A2 != nullptr) ? 2 : 1;
  for (int pass = 0; pass < npass; ++pass) {
    const float* Ap = pass ? A2 : A; const int la = pass ? lda2 : lda;
    const float* Bp = pass ? B2 : B; const int lb = pass ? ldb2 : ldb;
    const float sc = (pass && a2scale) ? __frcp_rn(a2scale[i0 + lr] + 1.f) : 1.f;
    const float* Arow = (pass == 0 && Ahi != nullptr && i0 >= 4096)
        ? (Ahi + (size_t)(i0 - 4096 + lr) * la)
        : (Ap + (size_t)(i0 + lr) * la);
    for (int k0 = 0; k0 < K; k0 += 16) {
      float4 ag = *(const float4*)(Arow + (k0 + lk));
      const float4 bg = *(const float4*)(Bp + (size_t)(j0 + lr) * lb + (k0 + lk));
      ag.x *= sc; ag.y *= sc; ag.z *= sc; ag.w *= sc;
      __syncthreads();
      As[lk+0][lr]=ag.x; As[lk+1][lr]=ag.y; As[lk+2][lr]=ag.z; As[lk+3][lr]=ag.w;
      Bs[lk+0][lr]=bg.x; Bs[lk+1][lr]=bg.y; Bs[lk+2][lr]=bg.z; Bs[lk+3][lr]=bg.w;
      __syncthreads();
#pragma unroll
      for (int k = 0; k < 16; ++k) {
        const float4 a4 = *(const float4*)&As[k][ty << 2];
        const float4 b4 = *(const float4*)&Bs[k][tx << 2];
        const float aa[4] = {a4.x, a4.y, a4.z, a4.w};
        const float bb[4] = {b4.x, b4.y, b4.z, b4.w};
#pragma unroll
        for (int ii = 0; ii < 4; ++ii)
#pragma unroll
          for (int jj = 0; jj < 4; ++jj)
            acc[ii][jj] += aa[ii] * bb[jj];
      }
    }
  }
  float badd[4] = {0.f, 0.f, 0.f, 0.f};
  if (bias) {
    const float4 t = *(const float4*)(bias + j0 + (tx << 2));
    badd[0]=t.x; badd[1]=t.y; badd[2]=t.z; badd[3]=t.w;
  }
#pragma unroll
  for (int ii = 0; ii < 4; ++ii) {
    float4 o;
    o.x = acc[ii][0] + badd[0];
    o.y = acc[ii][1] + badd[1];
    o.z = acc[ii][2] + badd[2];
    o.w = acc[ii][3] + badd[3];
    if (relu) { o.x=fmaxf(o.x,0.f); o.y=fmaxf(o.y,0.f); o.z=fmaxf(o.z,0.f); o.w=fmaxf(o.w,0.f); }
    if (Cb) {
      // obk-packed write: off(i,j) = (i>>5)<<12 | (j>>4)<<9 | (((j>>3)&1)<<5 | (i&31))<<3 | (j&7)
      const int i_ = i0 + (ty << 2) + ii;
      const int j_ = j0 + (tx << 2);
      const size_t off = ((size_t)(i_ >> 5) << 12) +
                         (size_t)(((j_ >> 4) << 9) +
                                  ((((( j_ >> 3) & 1) << 5) + (i_ & 31)) << 3) +
                                  (j_ & 7));
      ushort4 ob4;
      ob4.x = f2bf(o.x); ob4.y = f2bf(o.y); ob4.z = f2bf(o.z); ob4.w = f2bf(o.w);
      *(ushort4*)(Cb + off) = ob4;
    } else {
      const size_t off = (size_t)(i0 + (ty<<2) + ii) * ldc + j0 + (tx<<2);
      *(float4*)(C + off) = o;
    }
  }
}

// ---------------- CSR build (bucket edges by dst) ----------------
__global__ void count_k(const int* __restrict__ dst, int* __restrict__ deg, int E) {
  const int e = blockIdx.x * 256 + threadIdx.x;
  if (e < E) atomicAdd(&deg[dst[e]], 1);
}

__global__ __launch_bounds__(1024) void scan_k(const int* __restrict__ deg,
                                               int* __restrict__ rowptr,
                                               int* __restrict__ cursor) {
  __shared__ int sums[1024];
  const int t = threadIdx.x;
  const int4 d = *(const int4*)(deg + (t << 2));
  const int local = d.x + d.y + d.z + d.w;
  sums[t] = local;
  __syncthreads();
  for (int off = 1; off < 1024; off <<= 1) {
    int v = (t >= off) ? sums[t - off] : 0;
    __syncthreads();
    sums[t] += v;
    __syncthreads();
  }
  const int excl = sums[t] - local;
  const int o0 = excl, o1 = o0 + d.x, o2 = o1 + d.y, o3 = o2 + d.z;
  rowptr[(t<<2)+0]=o0; rowptr[(t<<2)+1]=o1; rowptr[(t<<2)+2]=o2; rowptr[(t<<2)+3]=o3;
  cursor[(t<<2)+0]=o0; cursor[(t<<2)+1]=o1; cursor[(t<<2)+2]=o2; cursor[(t<<2)+3]=o3;
  if (t == 1023) rowptr[4096] = sums[1023];
}

__global__ void fill_k(const int* __restrict__ src, const int* __restrict__ dst,
                       int* __restrict__ cursor, int* __restrict__ eidx, int E) {
  const int e = blockIdx.x * 256 + threadIdx.x;
  if (e < E) {
    const int p = atomicAdd(&cursor[dst[e]], 1);
    eidx[p] = src[e];
  }
}

// adjacency bitmap: bit(cell) for cell = dst*4096 + src (distinct via OR)
__global__ void bitmap_build_k(const int* __restrict__ src, const int* __restrict__ dst,
                               unsigned* __restrict__ bitmap, int E) {
  const int e = blockIdx.x * 256 + threadIdx.x;
  if (e < E) {
    const unsigned cell = ((unsigned)dst[e] << 12) + (unsigned)src[e];
    atomicOr(&bitmap[cell >> 5], 1u << (cell & 31));
  }
}

// segment_max as CSR gather. p >= 0 (relu'd) and every segment non-empty
// (self-loops), so init 0 reproduces the isfinite->0 semantics exactly.
__global__ void segmax_k(const float* __restrict__ p, const int* __restrict__ rowptr,
                         const int* __restrict__ eidx, float* __restrict__ hn, int F) {
  const int row = blockIdx.x, f = threadIdx.x;  // blockDim == F
  const int b = rowptr[row], e = rowptr[row + 1];
  float m = 0.f;
  for (int k = b; k < e; ++k) m = fmaxf(m, p[(size_t)eidx[k] * F + f]);
  hn[(size_t)row * F + f] = m;
}

// ---------------- small fused elementwise / reductions ----------------
__device__ inline float wave_sum(float v) {
#pragma unroll
  for (int o = 32; o > 0; o >>= 1) v += __shfl_down(v, o, 64);
  return v;
}

// relu + row l2norm; also zeroes the adjacency bitmap (1 word/thread exactly)
__global__ void relu_l2norm_k(const float* __restrict__ in, float* __restrict__ out,
                              unsigned* __restrict__ bitmap) {
  const int row = blockIdx.x, f = threadIdx.x;  // 128 threads, grid 4096
  bitmap[(blockIdx.x << 7) + f] = 0u;
  const float v = fmaxf(in[(size_t)row * 128 + f], 0.f);
  const float ss = wave_sum(v * v);
  __shared__ float w[2];
  if ((f & 63) == 0) w[f >> 6] = ss;
  __syncthreads();
  const float denom = fmaxf(sqrtf(w[0] + w[1]), 1e-12f);
  out[(size_t)row * 128 + f] = v / denom;
}

// nearest neighbor (excluding self); sqn comes from the diag of dots
__global__ void argmin_k(const float* __restrict__ dots, int* __restrict__ nn) {
  __shared__ float sqd[1024];
  const int i = blockIdx.x, tid = threadIdx.x;  // 256 threads
#pragma unroll
  for (int z = 0; z < 4; ++z) {
    const int j = (tid << 2) + z;
    sqd[j] = dots[(size_t)j * 1025];   // dots[j][j]
  }
  __syncthreads();
  float best = 3.402823466e38f; int bidx = 0x7fffffff;
  const float si = sqd[i];
  for (int j = tid; j < 1024; j += 256) {
    if (j == i) continue;
    float d2 = si + sqd[j] - 2.f * dots[(size_t)i * 1024 + j];
    d2 = fmaxf(d2, 0.f);
    if (d2 < best || (d2 == best && j < bidx)) { best = d2; bidx = j; }
  }
  __shared__ float bv[256]; __shared__ int bi[256];
  bv[tid] = best; bi[tid] = bidx;
  __syncthreads();
  for (int s = 128; s > 0; s >>= 1) {
    if (tid < s) {
      if (bv[tid+s] < bv[tid] || (bv[tid+s] == bv[tid] && bi[tid+s] < bi[tid])) {
        bv[tid] = bv[tid+s]; bi[tid] = bi[tid+s];
      }
    }
    __syncthreads();
  }
  if (tid == 0) nn[i] = bi[0];
}

// build synth rows (SMOTE interp) AND pack pvb fragments in one pass.
// grid 192 (one 32-row j-tile each); jt<128 sources h2, else computes synth
// (also materializing the f32 synth rows for the downstream gemms' A-operand).
__global__ __launch_bounds__(256) void build_pack_k(
    const float* __restrict__ h2, const int* __restrict__ nn,
    const float* __restrict__ gaps, float* __restrict__ synth,
    ushort_t* __restrict__ pvb) {
  __shared__ ushort_t s[4096];  // [32 j][128 f] bf16
  const int jt = blockIdx.x, tid = threadIdx.x;
  if (jt < 128) {
    const float* ip = h2 + ((size_t)jt << 12);
#pragma unroll
    for (int k = 0; k < 4; ++k) {
      const float4 v = *(const float4*)(ip + (tid << 4) + (k << 2));
      ushort4 h; h.x = f2bf(v.x); h.y = f2bf(v.y); h.z = f2bf(v.z); h.w = f2bf(v.w);
      *(ushort4*)(s + (tid << 4) + (k << 2)) = h;
    }
  } else {
    const int row = tid >> 3;                       // 0..31
    const int sIdx = ((jt - 128) << 5) + row;       // synth row (= 2i+rep)
    const int i = sIdx >> 1;
    const float g = gaps[sIdx];
    const int ni = nn[i];
#pragma unroll
    for (int k = 0; k < 4; ++k) {
      const int f = ((tid & 7) << 4) + (k << 2);
      const float4 c4 = *(const float4*)(h2 + (size_t)i * 128 + f);
      const float4 n4 = *(const float4*)(h2 + (size_t)ni * 128 + f);
      float4 v;
      v.x = c4.x + g * (n4.x - c4.x);
      v.y = c4.y + g * (n4.y - c4.y);
      v.z = c4.z + g * (n4.z - c4.z);
      v.w = c4.w + g * (n4.w - c4.w);
      *(float4*)(synth + (size_t)sIdx * 128 + f) = v;
      ushort4 h; h.x = f2bf(v.x); h.y = f2bf(v.y); h.z = f2bf(v.z); h.w = f2bf(v.w);
      *(ushort4*)(s + (row << 7) + f) = h;
    }
  }
  __syncthreads();
  const int u = tid & 31, ft = (tid >> 5) & 3, cc = tid >> 7;
  ushort_t* op = pvb + ((size_t)jt << 12) + (cc << 11) + (ft << 9);
#pragma unroll
  for (int m = 0; m < 2; ++m) {
    const int l = (u << 1) + m;
    const int f = (ft << 5) + (l & 31);
    const int jb = (cc << 4) + ((l >> 5) << 3);
    ushort4 o0, o1;
    o0.x = s[(jb + 0) * 128 + f]; o0.y = s[(jb + 1) * 128 + f];
    o0.z = s[(jb + 2) * 128 + f]; o0.w = s[(jb + 3) * 128 + f];
    o1.x = s[(jb + 4) * 128 + f]; o1.y = s[(jb + 5) * 128 + f];
    o1.z = s[(jb + 6) * 128 + f]; o1.w = s[(jb + 7) * 128 + f];
    *(ushort4*)(op + (l << 3) + 0) = o0;
    *(ushort4*)(op + (l << 3) + 4) = o1;
  }
}

// ---------------- fused MFMA v8: j-split + in-kernel edge loss ----------
// grid (192, 4): block = 4 waves sharing one 32-row i-tile, quarter q streams
// j-tiles [48q, 48q+48) (wave-interleaved). 3 waves/SIMD occupancy. Per tile,
// each lane tests its 16 cells against the adjacency bitmap (one 4B word) and
// accumulates s1/sub/ecount — edge_compact/edge_loss kernels are gone. Wave
// partials combined in LDS, then 4-way-contended coalesced atomics to neigh.
__global__ __launch_bounds__(256, 3) void fused_mfma(
    const ushort_t* __restrict__ obk,  // packed A/Q frags [192][8][64][8]
    const ushort_t* __restrict__ pvb,  // packed PV B frags [192][2][4][64][8]
    const unsigned* __restrict__ bitmap,
    float* __restrict__ neigh,         // 6144x128, pre-zeroed
    float* __restrict__ rowsum,        // 6144, pre-zeroed
    float* __restrict__ scal)          // [S_all, s1, -, sub, ecnt], pre-zeroed
{
  __shared__ float acc_lds[64][64];    // 16KB, e-major: [ft*16+r][lane]
  __shared__ float rsum_lds[32];
  __shared__ float wred[4][4];
  const int tid = threadIdx.x;
  const int w = tid >> 6;
  const int lane = tid & 63;
  const int lo = lane & 31, hi = lane >> 5;
  const int it = blockIdx.x;           // i-tile (32 rows)
  const int iw = it << 5;
  const int q = blockIdx.y;            // j-quarter
  const bool loss_i = (it < 128);      // i < 4096

  // zero LDS accumulators
  {
    const f32x4 z4 = (f32x4){0.f, 0.f, 0.f, 0.f};
#pragma unroll
    for (int z = 0; z < 4; ++z)
      *(f32x4*)(&acc_lds[0][0] + (tid << 4) + (z << 2)) = z4;
    if (tid < 32) rsum_lds[tid] = 0.f;
  }
  __syncthreads();

  // Q-frags (B operand of S^T), persistent
  bf16x8 qf[8];
  {
    const ushort_t* qp = obk + ((size_t)it << 12) + (lane << 3);
#pragma unroll
    for (int c = 0; c < 8; ++c) qf[c] = *(const bf16x8*)(qp + (c << 9));
  }
  f32x16 oacc[4];
#pragma unroll
  for (int ft = 0; ft < 4; ++ft)
#pragma unroll
    for (int r = 0; r < 16; ++r) oacc[ft][r] = 0.f;
  float rs = 0.f, s_all = 0.f, s1a = 0.f, suba = 0.f, ecf = 0.f;

  // K-frags for wave's first tile
  bf16x8 a[8];
  {
    const ushort_t* kp = obk + ((size_t)(q * 48 + w) << 12) + (lane << 3);
#pragma unroll
    for (int c = 0; c < 8; ++c) a[c] = *(const bf16x8*)(kp + (c << 9));
  }

  for (int k = 0; k < 12; ++k) {
    const int jt = q * 48 + (k << 2) + w;
    // PV B-frags for THIS tile — issue first (consumed after sigmoid)
    bf16x8 bvf[2][4];
    {
      const ushort_t* vp = pvb + ((size_t)jt << 12) + (lane << 3);
#pragma unroll
      for (int cc = 0; cc < 2; ++cc)
#pragma unroll
        for (int ft = 0; ft < 4; ++ft)
          bvf[cc][ft] = *(const bf16x8*)(vp + (cc << 11) + (ft << 9));
    }
    // S^T: two 4-deep accumulator chains
    f32x16 s0, s1;
#pragma unroll
    for (int r = 0; r < 16; ++r) { s0[r] = 0.f; s1[r] = 0.f; }
#pragma unroll
    for (int c = 0; c < 4; ++c) {
      s0 = __builtin_amdgcn_mfma_f32_32x32x16_bf16(a[c], qf[c], s0, 0, 0, 0);
      s1 = __builtin_amdgcn_mfma_f32_32x32x16_bf16(a[c + 4], qf[c + 4], s1, 0, 0, 0);
    }
    // prefetch next tile's K-frags
    if (k < 11) {
      const ushort_t* kp = obk + ((size_t)(jt + 4) << 12) + (lane << 3);
#pragma unroll
      for (int c = 0; c < 8; ++c) a[c] = *(const bf16x8*)(kp + (c << 9));
    }
    // adjacency word for this lane's i-row and tile (loss region only)
    const bool loss_t = loss_i && (jt < 128);
    unsigned word = 0u;
    if (loss_t) word = bitmap[((unsigned)(iw + lo) << 7) + (unsigned)jt];
    // sigmoid + threshold + rowsum + loss terms
    float p[16];
    if (loss_t) {
      ecf += (float)__popc(word & (0x0F0F0F0Fu << (hi << 2)));
#pragma unroll
      for (int r = 0; r < 16; ++r) {
        const float v = s0[r] + s1[r];
        const float sg = __builtin_amdgcn_rcpf(1.f + __expf(-v));
        const int jl = (r & 3) + ((r >> 2) << 3) + (hi << 2);
        const float e_ = (float)((word >> jl) & 1u);
        s_all += sg * sg;
        s1a  += e_ * (sg - 1.f) * (sg - 1.f);
        suba += e_ * sg * sg;
        const float tv = (v >= 0.f) ? sg : 0.f;   // sg>=0.5 <=> v>=0
        p[r] = tv; rs += tv;
      }
    } else {
#pragma unroll
      for (int r = 0; r < 16; ++r) {
        const float v = s0[r] + s1[r];
        const float sg = __builtin_amdgcn_rcpf(1.f + __expf(-v));
        const float tv = (v >= 0.f) ? sg : 0.f;
        p[r] = tv; rs += tv;
      }
    }
    // pack P -> bf16 PV A-frags: cvt_pk pairs + permlane32_swap (T12)
#pragma unroll
    for (int cc = 0; cc < 2; ++cc) {
      const int b8 = cc << 3;
      unsigned c01, c23, c45, c67;
      asm("v_cvt_pk_bf16_f32 %0, %1, %2" : "=v"(c01) : "v"(p[b8+0]), "v"(p[b8+1]));
      asm("v_cvt_pk_bf16_f32 %0, %1, %2" : "=v"(c23) : "v"(p[b8+2]), "v"(p[b8+3]));
      asm("v_cvt_pk_bf16_f32 %0, %1, %2" : "=v"(c45) : "v"(p[b8+4]), "v"(p[b8+5]));
      asm("v_cvt_pk_bf16_f32 %0, %1, %2" : "=v"(c67) : "v"(p[b8+6]), "v"(p[b8+7]));
      const auto w0 = __builtin_amdgcn_permlane32_swap((int)c01, (int)c45, false, false);
      const auto w1 = __builtin_amdgcn_permlane32_swap((int)c23, (int)c67, false, false);
      union { int i[4]; bf16x8 h; } u;
      u.i[0] = w0[0]; u.i[1] = w1[0]; u.i[2] = w0[1]; u.i[3] = w1[1];
#pragma unroll
      for (int ft = 0; ft < 4; ++ft)
        oacc[ft] = __builtin_amdgcn_mfma_f32_32x32x16_bf16(u.h, bvf[cc][ft], oacc[ft], 0, 0, 0);
    }
  }
  // ---- combine the 4 waves' partials in LDS ----
#pragma unroll
  for (int ft = 0; ft < 4; ++ft)
#pragma unroll
    for (int r = 0; r < 16; ++r)
      atomicAdd(&acc_lds[(ft << 4) + r][lane], oacc[ft][r]);
  rs += __shfl_xor(rs, 32, 64);
  if (hi == 0) atomicAdd(&rsum_lds[lo], rs);
  // scalar partials: wave-reduce, stash per wave
  {
    float v0 = wave_sum(s_all), v1 = wave_sum(s1a), v2 = wave_sum(suba), v3 = wave_sum(ecf);
    if (lane == 0) { wred[w][0] = v0; wred[w][1] = v1; wred[w][2] = v2; wred[w][3] = v3; }
  }
  __syncthreads();
  // ---- flush: combined 32x128 tile -> global atomics (4-way across q) ----
#pragma unroll
  for (int z = 0; z < 16; ++z) {
    const int idx = (z << 8) + tid;    // 0..4095
    const int g = idx >> 7;            // row 0..31
    const int c = idx & 127;           // col 0..127
    const int ft = c >> 5, lo_ = c & 31;
    const int hig = (g >> 2) & 1;
    const int r = (g & 3) + ((g >> 3) << 2);
    atomicAdd(&neigh[(size_t)(iw + g) * 128 + c], acc_lds[(ft << 4) + r][(hig << 5) + lo_]);
  }
  if (tid < 32) atomicAdd(&rowsum[iw + tid], rsum_lds[tid]);
  if (tid < 4) {
    const float t = wred[0][tid] + wred[1][tid] + wred[2][tid] + wred[3][tid];
    const int dst = (tid == 0) ? 0 : (tid == 1) ? 1 : (tid == 2) ? 3 : 4;
    atomicAdd(&scal[dst], t);
  }
}

// logits + y + final loss in one launch (ecount now float in scal[4])
__global__ void logits_y_loss_k(const float* __restrict__ hc, const float* __restrict__ Wclf,
                                const float* __restrict__ bclf, const int* __restrict__ labels,
                                const float* __restrict__ scal,
                                float* __restrict__ outp) {
  const int i = blockIdx.x, f = threadIdx.x;  // 128 threads
  const float h = hc[(size_t)i * 128 + f];
  const float v0 = wave_sum(h * Wclf[f]);
  const float v1 = wave_sum(h * Wclf[128 + f]);
  __shared__ float w0[2], w1[2];
  if ((f & 63) == 0) { w0[f >> 6] = v0; w1[f >> 6] = v1; }
  __syncthreads();
  if (f == 0) {
    outp[(size_t)i * 2 + 0] = w0[0] + w0[1] + bclf[0];
    outp[(size_t)i * 2 + 1] = w1[0] + w1[1] + bclf[1];
    outp[12288 + i] = (i < 4096) ? (float)labels[i] : 1.f;
    if (i == 0) {
      const float cnt = scal[4];
      const float neg_w = cnt / (16777216.f - cnt);
      outp[18432] = neg_w * (scal[0] - scal[3]) + scal[1];
    }
  }
}

// ---------------- launcher ----------------
extern "C" void kernel_launch(void* const* d_in, const int* in_sizes, int n_in,
                              void* d_out, int out_size, void* d_ws, size_t ws_size,
                              hipStream_t stream) {
  const float* feat     = (const float*)d_in[0];
  const int*   src      = (const int*)d_in[2];
  const int*   dst      = (const int*)d_in[3];
  const int*   labels   = (const int*)d_in[4];
  const float* W_pool0  = (const float*)d_in[5];
  const float* b_pool0  = (const float*)d_in[6];
  const float* W_self0  = (const float*)d_in[7];
  const float* W_neigh0 = (const float*)d_in[8];
  const float* b0       = (const float*)d_in[9];
  const float* W_pool1  = (const float*)d_in[10];
  const float* b_pool1  = (const float*)d_in[11];
  const float* W_self1  = (const float*)d_in[12];
  const float* W_neigh1 = (const float*)d_in[13];
  const float* b1       = (const float*)d_in[14];
  const float* de_w     = (const float*)d_in[15];
  const float* W_conv   = (const float*)d_in[16];
  const float* W_clf    = (const float*)d_in[17];
  const float* b_clf    = (const float*)d_in[18];
  const float* gaps     = (const float*)d_in[19];
  const int E = in_sizes[2];  // 69632 (E + self-loops)

  float* ws = (float*)d_ws;
  float* p0       = ws + WS_P0;
  float* dots     = ws + WS_DOTS;
  ushort_t* obk   = (ushort_t*)(ws + WS_OBK);
  float* hn0      = ws + WS_HN0;
  unsigned* bitmap= (unsigned*)(ws + WS_BITMAP);
  float* hc       = ws + WS_HC;
  float* h1       = ws + WS_H1;
  float* h1n      = ws + WS_H1N;
  float* p1       = ws + WS_P1;
  ushort_t* pvb   = (ushort_t*)(ws + WS_PVB);
  float* hn1      = ws + WS_HN1;
  float* h2       = ws + WS_H2;
  float* synth    = ws + WS_X;
  float* neigh    = ws + WS_NEIGH;
  float* rowsum   = ws + WS_ROWSUM;
  float* scal     = ws + WS_SCAL;
  int* deg        = (int*)(ws + WS_DEG);
  int* nn         = (int*)(ws + WS_NN);
  int* cursor     = (int*)(ws + WS_CUR);
  int* rowptr     = (int*)(ws + WS_ROWPTR);
  int* eidx       = (int*)(ws + WS_EIDX);

  float* outp = (float*)d_out;
  const dim3 blk(256);

  // one contiguous zero region: neigh + rowsum + scal + deg
  hipMemsetAsync(neigh, 0, (size_t)(WS_DEG + 4096 - WS_NEIGH) * 4, stream);

  // CSR bucket-by-dst
  count_k<<<(E + 255) / 256, blk, 0, stream>>>(dst, deg, E);
  scan_k<<<1, 1024, 0, stream>>>(deg, rowptr, cursor);
  fill_k<<<(E + 255) / 256, blk, 0, stream>>>(src, dst, cursor, eidx, E);

  // layer 0
  gemm_nt<<<dim3(4, 64), blk, 0, stream>>>(feat, 256, W_pool0, 256,
                                           nullptr, 0, nullptr, 0,
                                           b_pool0, p0, 256, 256, 1, nullptr, nullptr, nullptr);
  segmax_k<<<4096, 256, 0, stream>>>(p0, rowptr, eidx, hn0, 256);
  gemm_nt<<<dim3(2, 64), blk, 0, stream>>>(feat, 256, W_self0, 256,
                                           hn0, 256, W_neigh0, 256,
                                           b0, h1, 128, 256, 0, nullptr, nullptr, nullptr);
  // relu+l2norm; also zeroes the bitmap (hn0 region is dead from here)
  relu_l2norm_k<<<4096, 128, 0, stream>>>(h1, h1n, bitmap);
  bitmap_build_k<<<(E + 255) / 256, blk, 0, stream>>>(src, dst, bitmap, E);

  // layer 1
  gemm_nt<<<dim3(2, 64), blk, 0, stream>>>(h1n, 128, W_pool1, 128,
                                           nullptr, 0, nullptr, 0,
                                           b_pool1, p1, 128, 128, 1, nullptr, nullptr, nullptr);
  segmax_k<<<4096, 128, 0, stream>>>(p1, rowptr, eidx, hn1, 128);
  gemm_nt<<<dim3(2, 64), blk, 0, stream>>>(h1n, 128, W_self1, 128,
                                           hn1, 128, W_neigh1, 128,
                                           b1, h2, 128, 128, 0, nullptr, nullptr, nullptr);

  // SMOTE: dots gemm (diag doubles as sqn), argmin, synth+pvb pack
  gemm_nt<<<dim3(16, 16), blk, 0, stream>>>(h2, 128, h2, 128,
                                            nullptr, 0, nullptr, 0,
                                            nullptr, dots, 1024, 128, 0, nullptr, nullptr, nullptr);
  argmin_k<<<1024, 256, 0, stream>>>(dots, nn);
  build_pack_k<<<192, blk, 0, stream>>>(h2, nn, gaps, synth, pvb);

  // decoder gemm writes obk-packed bf16 directly (dots dead -> obk region ok)
  gemm_nt<<<dim3(2, 96), blk, 0, stream>>>(h2, 128, de_w, 128,
                                           nullptr, 0, nullptr, 0,
                                           nullptr, nullptr, 0, 128, 0, obk, nullptr, synth);
  // dense fused pass: S_all/s1/sub/ecount + thresholded P@x + rowsum
  fused_mfma<<<dim3(192, 4), blk, 0, stream>>>(obk, pvb, bitmap, neigh, rowsum, scal);

  // classifier: neigh/(rowsum+1) folded into the gemm's A2 path
  gemm_nt<<<dim3(2, 96), blk, 0, stream>>>(h2, 128, W_conv, 256,
                                           neigh, 128, W_conv + 128, 256,
                                           nullptr, hc, 128, 128, 0, nullptr, rowsum, synth);
  logits_y_loss_k<<<6144, 128, 0, stream>>>(hc, W_clf, b_clf, labels, scal, outp);

  (void)n_in; (void)out_size; (void)ws_size; (void)in_sizes;
}

// Round 7
// 403.782 us; speedup vs baseline: 1.3548x; 1.3548x over previous
//
#include <hip/hip_runtime.h>
#include <cstddef>

typedef unsigned short ushort_t;
typedef __attribute__((ext_vector_type(8))) short bf16x8;
typedef __attribute__((ext_vector_type(4))) float f32x4;
typedef __attribute__((ext_vector_type(16))) float f32x16;

// ---------------- workspace layout (float offsets) ----------------
// [0..1048576): p0 (4096x256) -> dots (1024x1024); obk (packed bf16 6144x128 =
//               393216 f) at +524288 once dots is dead (after argmin).
#define WS_P0     0u
#define WS_DOTS   0u
#define WS_OBK    524288u
#define WS_HN0    1048576u   /* 4096x256; -> bitmap (524288 words) after h1 gemm; -> hc after fused */
#define WS_BITMAP 1048576u
#define WS_HC     1048576u
#define WS_H1     2097152u   /* 4096x128 */
#define WS_H1N    2621440u   /* 4096x128 */
#define WS_P1     3145728u   /* 4096x128; -> pvb (bf16 packed 192 tiles = 393216 f) */
#define WS_PVB    3145728u
#define WS_HN1    3670016u   /* 4096x128 */
#define WS_H2     4194304u   /* 4096x128 (live to the end now) */
#define WS_X      4718592u   /* synth 2048x128 (rows >= 4096 of x) */
#define WS_OB     5505024u   /* (unused now) */
// ---- contiguous zero region (one memset): ----
#define WS_NEIGH  6291456u   /* 786432 */
#define WS_ROWSUM 7077888u   /* 6144 */
#define WS_SCAL   7084032u   /* 16 floats: [S_all, s1, -, sub, ecount_f] */
#define WS_DEG    7084048u   /* int 4096 */
// ---- end zero region ----
#define WS_NN     7088144u   /* int 1024 */
#define WS_CUR    7089168u   /* int 4096 */
#define WS_ROWPTR 7093264u   /* int 4097 */
#define WS_EIDX   7097361u   /* int 69632 */

__device__ inline ushort_t f2bf(float f) {
  unsigned u = __float_as_uint(f);
  u += 0x7fff + ((u >> 16) & 1);   // round-to-nearest-even
  return (ushort_t)(u >> 16);
}

// ---------------- generic NT GEMM: C = act(A@B^T (+ A2@B2^T) + bias) -------
// Ahi: optional second A base for rows >= 4096 (split h2/synth, block-uniform).
// Cb: when set, write bf16 output in the obk-packed fragment layout.
__global__ __launch_bounds__(256, 2) void gemm_nt(
    const float* __restrict__ A, int lda,
    const float* __restrict__ B, int ldb,
    const float* __restrict__ A2, int lda2,
    const float* __restrict__ B2, int ldb2,
    const float* __restrict__ bias,
    float* __restrict__ C, int ldc,
    int K, int relu,
    ushort_t* __restrict__ Cb,
    const float* __restrict__ a2scale,
    const float* __restrict__ Ahi)
{
  __shared__ float As[16][68];
  __shared__ float Bs[16][68];
  const int tid = threadIdx.x;
  const int tx = tid & 15, ty = tid >> 4;
  const int lr = tid >> 2;
  const int lk = (tid & 3) << 2;
  const int i0 = blockIdx.y << 6;
  const int j0 = blockIdx.x << 6;
  float acc[4][4] = {};
  const int npass = (A2 != nullptr) ? 2 : 1;
  for (int pass = 0; pass < npass; ++pass) {
    const float* Ap = pass ? A2 : A; const int la = pass ? lda2 : lda;
    const float* Bp = pass ? B2 : B; const int lb = pass ? ldb2 : ldb;
    const float sc = (pass && a2scale) ? __frcp_rn(a2scale[i0 + lr] + 1.f) : 1.f;
    const float* Arow = (pass == 0 && Ahi != nullptr && i0 >= 4096)
        ? (Ahi + (size_t)(i0 - 4096 + lr) * la)
        : (Ap + (size_t)(i0 + lr) * la);
    for (int k0 = 0; k0 < K; k0 += 16) {
      float4 ag = *(const float4*)(Arow + (k0 + lk));
      const float4 bg = *(const float4*)(Bp + (size_t)(j0 + lr) * lb + (k0 + lk));
      ag.x *= sc; ag.y *= sc; ag.z *= sc; ag.w *= sc;
      __syncthreads();
      As[lk+0][lr]=ag.x; As[lk+1][lr]=ag.y; As[lk+2][lr]=ag.z; As[lk+3][lr]=ag.w;
      Bs[lk+0][lr]=bg.x; Bs[lk+1][lr]=bg.y; Bs[lk+2][lr]=bg.z; Bs[lk+3][lr]=bg.w;
      __syncthreads();
#pragma unroll
      for (int k = 0; k < 16; ++k) {
        const float4 a4 = *(const float4*)&As[k][ty << 2];
        const float4 b4 = *(const float4*)&Bs[k][tx << 2];
        const float aa[4] = {a4.x, a4.y, a4.z, a4.w};
        const float bb[4] = {b4.x, b4.y, b4.z, b4.w};
#pragma unroll
        for (int ii = 0; ii < 4; ++ii)
#pragma unroll
          for (int jj = 0; jj < 4; ++jj)
            acc[ii][jj] += aa[ii] * bb[jj];
      }
    }
  }
  float badd[4] = {0.f, 0.f, 0.f, 0.f};
  if (bias) {
    const float4 t = *(const float4*)(bias + j0 + (tx << 2));
    badd[0]=t.x; badd[1]=t.y; badd[2]=t.z; badd[3]=t.w;
  }
#pragma unroll
  for (int ii = 0; ii < 4; ++ii) {
    float4 o;
    o.x = acc[ii][0] + badd[0];
    o.y = acc[ii][1] + badd[1];
    o.z = acc[ii][2] + badd[2];
    o.w = acc[ii][3] + badd[3];
    if (relu) { o.x=fmaxf(o.x,0.f); o.y=fmaxf(o.y,0.f); o.z=fmaxf(o.z,0.f); o.w=fmaxf(o.w,0.f); }
    if (Cb) {
      // obk-packed write: off(i,j) = (i>>5)<<12 | (j>>4)<<9 | (((j>>3)&1)<<5 | (i&31))<<3 | (j&7)
      const int i_ = i0 + (ty << 2) + ii;
      const int j_ = j0 + (tx << 2);
      const size_t off = ((size_t)(i_ >> 5) << 12) +
                         (size_t)(((j_ >> 4) << 9) +
                                  ((((( j_ >> 3) & 1) << 5) + (i_ & 31)) << 3) +
                                  (j_ & 7));
      ushort4 ob4;
      ob4.x = f2bf(o.x); ob4.y = f2bf(o.y); ob4.z = f2bf(o.z); ob4.w = f2bf(o.w);
      *(ushort4*)(Cb + off) = ob4;
    } else {
      const size_t off = (size_t)(i0 + (ty<<2) + ii) * ldc + j0 + (tx<<2);
      *(float4*)(C + off) = o;
    }
  }
}

// ---------------- CSR build (bucket edges by dst) ----------------
__global__ void count_k(const int* __restrict__ dst, int* __restrict__ deg, int E) {
  const int e = blockIdx.x * 256 + threadIdx.x;
  if (e < E) atomicAdd(&deg[dst[e]], 1);
}

__global__ __launch_bounds__(1024) void scan_k(const int* __restrict__ deg,
                                               int* __restrict__ rowptr,
                                               int* __restrict__ cursor) {
  __shared__ int sums[1024];
  const int t = threadIdx.x;
  const int4 d = *(const int4*)(deg + (t << 2));
  const int local = d.x + d.y + d.z + d.w;
  sums[t] = local;
  __syncthreads();
  for (int off = 1; off < 1024; off <<= 1) {
    int v = (t >= off) ? sums[t - off] : 0;
    __syncthreads();
    sums[t] += v;
    __syncthreads();
  }
  const int excl = sums[t] - local;
  const int o0 = excl, o1 = o0 + d.x, o2 = o1 + d.y, o3 = o2 + d.z;
  rowptr[(t<<2)+0]=o0; rowptr[(t<<2)+1]=o1; rowptr[(t<<2)+2]=o2; rowptr[(t<<2)+3]=o3;
  cursor[(t<<2)+0]=o0; cursor[(t<<2)+1]=o1; cursor[(t<<2)+2]=o2; cursor[(t<<2)+3]=o3;
  if (t == 1023) rowptr[4096] = sums[1023];
}

__global__ void fill_k(const int* __restrict__ src, const int* __restrict__ dst,
                       int* __restrict__ cursor, int* __restrict__ eidx, int E) {
  const int e = blockIdx.x * 256 + threadIdx.x;
  if (e < E) {
    const int p = atomicAdd(&cursor[dst[e]], 1);
    eidx[p] = src[e];
  }
}

// adjacency bitmap: bit(cell) for cell = dst*4096 + src (distinct via OR)
__global__ void bitmap_build_k(const int* __restrict__ src, const int* __restrict__ dst,
                               unsigned* __restrict__ bitmap, int E) {
  const int e = blockIdx.x * 256 + threadIdx.x;
  if (e < E) {
    const unsigned cell = ((unsigned)dst[e] << 12) + (unsigned)src[e];
    atomicOr(&bitmap[cell >> 5], 1u << (cell & 31));
  }
}

// segment_max as CSR gather. p >= 0 (relu'd) and every segment non-empty
// (self-loops), so init 0 reproduces the isfinite->0 semantics exactly.
__global__ void segmax_k(const float* __restrict__ p, const int* __restrict__ rowptr,
                         const int* __restrict__ eidx, float* __restrict__ hn, int F) {
  const int row = blockIdx.x, f = threadIdx.x;  // blockDim == F
  const int b = rowptr[row], e = rowptr[row + 1];
  float m = 0.f;
  for (int k = b; k < e; ++k) m = fmaxf(m, p[(size_t)eidx[k] * F + f]);
  hn[(size_t)row * F + f] = m;
}

// ---------------- small fused elementwise / reductions ----------------
__device__ inline float wave_sum(float v) {
#pragma unroll
  for (int o = 32; o > 0; o >>= 1) v += __shfl_down(v, o, 64);
  return v;
}

// relu + row l2norm; also zeroes the adjacency bitmap (1 word/thread exactly)
__global__ void relu_l2norm_k(const float* __restrict__ in, float* __restrict__ out,
                              unsigned* __restrict__ bitmap) {
  const int row = blockIdx.x, f = threadIdx.x;  // 128 threads, grid 4096
  bitmap[(blockIdx.x << 7) + f] = 0u;
  const float v = fmaxf(in[(size_t)row * 128 + f], 0.f);
  const float ss = wave_sum(v * v);
  __shared__ float w[2];
  if ((f & 63) == 0) w[f >> 6] = ss;
  __syncthreads();
  const float denom = fmaxf(sqrtf(w[0] + w[1]), 1e-12f);
  out[(size_t)row * 128 + f] = v / denom;
}

// nearest neighbor (excluding self); sqn comes from the diag of dots
__global__ void argmin_k(const float* __restrict__ dots, int* __restrict__ nn) {
  __shared__ float sqd[1024];
  const int i = blockIdx.x, tid = threadIdx.x;  // 256 threads
#pragma unroll
  for (int z = 0; z < 4; ++z) {
    const int j = (tid << 2) + z;
    sqd[j] = dots[(size_t)j * 1025];   // dots[j][j]
  }
  __syncthreads();
  float best = 3.402823466e38f; int bidx = 0x7fffffff;
  const float si = sqd[i];
  for (int j = tid; j < 1024; j += 256) {
    if (j == i) continue;
    float d2 = si + sqd[j] - 2.f * dots[(size_t)i * 1024 + j];
    d2 = fmaxf(d2, 0.f);
    if (d2 < best || (d2 == best && j < bidx)) { best = d2; bidx = j; }
  }
  __shared__ float bv[256]; __shared__ int bi[256];
  bv[tid] = best; bi[tid] = bidx;
  __syncthreads();
  for (int s = 128; s > 0; s >>= 1) {
    if (tid < s) {
      if (bv[tid+s] < bv[tid] || (bv[tid+s] == bv[tid] && bi[tid+s] < bi[tid])) {
        bv[tid] = bv[tid+s]; bi[tid] = bi[tid+s];
      }
    }
    __syncthreads();
  }
  if (tid == 0) nn[i] = bi[0];
}

// build synth rows (SMOTE interp) AND pack pvb fragments in one pass.
// grid 192 (one 32-row j-tile each); jt<128 sources h2, else computes synth
// (also materializing the f32 synth rows for the downstream gemms' A-operand).
__global__ __launch_bounds__(256) void build_pack_k(
    const float* __restrict__ h2, const int* __restrict__ nn,
    const float* __restrict__ gaps, float* __restrict__ synth,
    ushort_t* __restrict__ pvb) {
  __shared__ ushort_t s[4096];  // [32 j][128 f] bf16
  const int jt = blockIdx.x, tid = threadIdx.x;
  if (jt < 128) {
    const float* ip = h2 + ((size_t)jt << 12);
#pragma unroll
    for (int k = 0; k < 4; ++k) {
      const float4 v = *(const float4*)(ip + (tid << 4) + (k << 2));
      ushort4 h; h.x = f2bf(v.x); h.y = f2bf(v.y); h.z = f2bf(v.z); h.w = f2bf(v.w);
      *(ushort4*)(s + (tid << 4) + (k << 2)) = h;
    }
  } else {
    const int row = tid >> 3;                       // 0..31
    const int sIdx = ((jt - 128) << 5) + row;       // synth row (= 2i+rep)
    const int i = sIdx >> 1;
    const float g = gaps[sIdx];
    const int ni = nn[i];
#pragma unroll
    for (int k = 0; k < 4; ++k) {
      const int f = ((tid & 7) << 4) + (k << 2);
      const float4 c4 = *(const float4*)(h2 + (size_t)i * 128 + f);
      const float4 n4 = *(const float4*)(h2 + (size_t)ni * 128 + f);
      float4 v;
      v.x = c4.x + g * (n4.x - c4.x);
      v.y = c4.y + g * (n4.y - c4.y);
      v.z = c4.z + g * (n4.z - c4.z);
      v.w = c4.w + g * (n4.w - c4.w);
      *(float4*)(synth + (size_t)sIdx * 128 + f) = v;
      ushort4 h; h.x = f2bf(v.x); h.y = f2bf(v.y); h.z = f2bf(v.z); h.w = f2bf(v.w);
      *(ushort4*)(s + (row << 7) + f) = h;
    }
  }
  __syncthreads();
  const int u = tid & 31, ft = (tid >> 5) & 3, cc = tid >> 7;
  ushort_t* op = pvb + ((size_t)jt << 12) + (cc << 11) + (ft << 9);
#pragma unroll
  for (int m = 0; m < 2; ++m) {
    const int l = (u << 1) + m;
    const int f = (ft << 5) + (l & 31);
    const int jb = (cc << 4) + ((l >> 5) << 3);
    ushort4 o0, o1;
    o0.x = s[(jb + 0) * 128 + f]; o0.y = s[(jb + 1) * 128 + f];
    o0.z = s[(jb + 2) * 128 + f]; o0.w = s[(jb + 3) * 128 + f];
    o1.x = s[(jb + 4) * 128 + f]; o1.y = s[(jb + 5) * 128 + f];
    o1.z = s[(jb + 6) * 128 + f]; o1.w = s[(jb + 7) * 128 + f];
    *(ushort4*)(op + (l << 3) + 0) = o0;
    *(ushort4*)(op + (l << 3) + 4) = o1;
  }
}

// ---------------- fused MFMA v8b: j-split + in-kernel edge loss ----------
// v8 with the register-budget fix: __launch_bounds__(256,2). Round 6's (256,3)
// capped VGPR+AGPR at 170 < the ~176 the loop needs -> scratch spills -> 1GB
// of HBM traffic (FETCH 373MB/WRITE 607MB, VGPR_Count 84). (256,2) is the
// proven no-spill budget for this loop body (v5/v7: VGPR 112 + AGPR 64).
__global__ __launch_bounds__(256, 2) void fused_mfma(
    const ushort_t* __restrict__ obk,  // packed A/Q frags [192][8][64][8]
    const ushort_t* __restrict__ pvb,  // packed PV B frags [192][2][4][64][8]
    const unsigned* __restrict__ bitmap,
    float* __restrict__ neigh,         // 6144x128, pre-zeroed
    float* __restrict__ rowsum,        // 6144, pre-zeroed
    float* __restrict__ scal)          // [S_all, s1, -, sub, ecnt], pre-zeroed
{
  __shared__ float acc_lds[64][64];    // 16KB, e-major: [ft*16+r][lane]
  __shared__ float rsum_lds[32];
  __shared__ float wred[4][4];
  const int tid = threadIdx.x;
  const int w = tid >> 6;
  const int lane = tid & 63;
  const int lo = lane & 31, hi = lane >> 5;
  const int it = blockIdx.x;           // i-tile (32 rows)
  const int iw = it << 5;
  const int q = blockIdx.y;            // j-quarter
  const bool loss_i = (it < 128);      // i < 4096

  // zero LDS accumulators
  {
    const f32x4 z4 = (f32x4){0.f, 0.f, 0.f, 0.f};
#pragma unroll
    for (int z = 0; z < 4; ++z)
      *(f32x4*)(&acc_lds[0][0] + (tid << 4) + (z << 2)) = z4;
    if (tid < 32) rsum_lds[tid] = 0.f;
  }
  __syncthreads();

  // Q-frags (B operand of S^T), persistent
  bf16x8 qf[8];
  {
    const ushort_t* qp = obk + ((size_t)it << 12) + (lane << 3);
#pragma unroll
    for (int c = 0; c < 8; ++c) qf[c] = *(const bf16x8*)(qp + (c << 9));
  }
  f32x16 oacc[4];
#pragma unroll
  for (int ft = 0; ft < 4; ++ft)
#pragma unroll
    for (int r = 0; r < 16; ++r) oacc[ft][r] = 0.f;
  float rs = 0.f, s_all = 0.f, s1a = 0.f, suba = 0.f, ecf = 0.f;

  // K-frags for wave's first tile
  bf16x8 a[8];
  {
    const ushort_t* kp = obk + ((size_t)(q * 48 + w) << 12) + (lane << 3);
#pragma unroll
    for (int c = 0; c < 8; ++c) a[c] = *(const bf16x8*)(kp + (c << 9));
  }

  for (int k = 0; k < 12; ++k) {
    const int jt = q * 48 + (k << 2) + w;
    // PV B-frags for THIS tile — issue first (consumed after sigmoid)
    bf16x8 bvf[2][4];
    {
      const ushort_t* vp = pvb + ((size_t)jt << 12) + (lane << 3);
#pragma unroll
      for (int cc = 0; cc < 2; ++cc)
#pragma unroll
        for (int ft = 0; ft < 4; ++ft)
          bvf[cc][ft] = *(const bf16x8*)(vp + (cc << 11) + (ft << 9));
    }
    // S^T: two 4-deep accumulator chains
    f32x16 s0, s1;
#pragma unroll
    for (int r = 0; r < 16; ++r) { s0[r] = 0.f; s1[r] = 0.f; }
#pragma unroll
    for (int c = 0; c < 4; ++c) {
      s0 = __builtin_amdgcn_mfma_f32_32x32x16_bf16(a[c], qf[c], s0, 0, 0, 0);
      s1 = __builtin_amdgcn_mfma_f32_32x32x16_bf16(a[c + 4], qf[c + 4], s1, 0, 0, 0);
    }
    // prefetch next tile's K-frags
    if (k < 11) {
      const ushort_t* kp = obk + ((size_t)(jt + 4) << 12) + (lane << 3);
#pragma unroll
      for (int c = 0; c < 8; ++c) a[c] = *(const bf16x8*)(kp + (c << 9));
    }
    // adjacency word for this lane's i-row and tile (loss region only)
    const bool loss_t = loss_i && (jt < 128);
    unsigned word = 0u;
    if (loss_t) word = bitmap[((unsigned)(iw + lo) << 7) + (unsigned)jt];
    // sigmoid + threshold + rowsum + loss terms
    float p[16];
    if (loss_t) {
      ecf += (float)__popc(word & (0x0F0F0F0Fu << (hi << 2)));
#pragma unroll
      for (int r = 0; r < 16; ++r) {
        const float v = s0[r] + s1[r];
        const float sg = __builtin_amdgcn_rcpf(1.f + __expf(-v));
        const int jl = (r & 3) + ((r >> 2) << 3) + (hi << 2);
        const float e_ = (float)((word >> jl) & 1u);
        s_all += sg * sg;
        s1a  += e_ * (sg - 1.f) * (sg - 1.f);
        suba += e_ * sg * sg;
        const float tv = (v >= 0.f) ? sg : 0.f;   // sg>=0.5 <=> v>=0
        p[r] = tv; rs += tv;
      }
    } else {
#pragma unroll
      for (int r = 0; r < 16; ++r) {
        const float v = s0[r] + s1[r];
        const float sg = __builtin_amdgcn_rcpf(1.f + __expf(-v));
        const float tv = (v >= 0.f) ? sg : 0.f;
        p[r] = tv; rs += tv;
      }
    }
    // pack P -> bf16 PV A-frags: cvt_pk pairs + permlane32_swap (T12)
#pragma unroll
    for (int cc = 0; cc < 2; ++cc) {
      const int b8 = cc << 3;
      unsigned c01, c23, c45, c67;
      asm("v_cvt_pk_bf16_f32 %0, %1, %2" : "=v"(c01) : "v"(p[b8+0]), "v"(p[b8+1]));
      asm("v_cvt_pk_bf16_f32 %0, %1, %2" : "=v"(c23) : "v"(p[b8+2]), "v"(p[b8+3]));
      asm("v_cvt_pk_bf16_f32 %0, %1, %2" : "=v"(c45) : "v"(p[b8+4]), "v"(p[b8+5]));
      asm("v_cvt_pk_bf16_f32 %0, %1, %2" : "=v"(c67) : "v"(p[b8+6]), "v"(p[b8+7]));
      const auto w0 = __builtin_amdgcn_permlane32_swap((int)c01, (int)c45, false, false);
      const auto w1 = __builtin_amdgcn_permlane32_swap((int)c23, (int)c67, false, false);
      union { int i[4]; bf16x8 h; } u;
      u.i[0] = w0[0]; u.i[1] = w1[0]; u.i[2] = w0[1]; u.i[3] = w1[1];
#pragma unroll
      for (int ft = 0; ft < 4; ++ft)
        oacc[ft] = __builtin_amdgcn_mfma_f32_32x32x16_bf16(u.h, bvf[cc][ft], oacc[ft], 0, 0, 0);
    }
  }
  // ---- combine the 4 waves' partials in LDS ----
#pragma unroll
  for (int ft = 0; ft < 4; ++ft)
#pragma unroll
    for (int r = 0; r < 16; ++r)
      atomicAdd(&acc_lds[(ft << 4) + r][lane], oacc[ft][r]);
  rs += __shfl_xor(rs, 32, 64);
  if (hi == 0) atomicAdd(&rsum_lds[lo], rs);
  // scalar partials: wave-reduce, stash per wave
  {
    float v0 = wave_sum(s_all), v1 = wave_sum(s1a), v2 = wave_sum(suba), v3 = wave_sum(ecf);
    if (lane == 0) { wred[w][0] = v0; wred[w][1] = v1; wred[w][2] = v2; wred[w][3] = v3; }
  }
  __syncthreads();
  // ---- flush: combined 32x128 tile -> global atomics (4-way across q) ----
#pragma unroll
  for (int z = 0; z < 16; ++z) {
    const int idx = (z << 8) + tid;    // 0..4095
    const int g = idx >> 7;            // row 0..31
    const int c = idx & 127;           // col 0..127
    const int ft = c >> 5, lo_ = c & 31;
    const int hig = (g >> 2) & 1;
    const int r = (g & 3) + ((g >> 3) << 2);
    atomicAdd(&neigh[(size_t)(iw + g) * 128 + c], acc_lds[(ft << 4) + r][(hig << 5) + lo_]);
  }
  if (tid < 32) atomicAdd(&rowsum[iw + tid], rsum_lds[tid]);
  if (tid < 4) {
    const float t = wred[0][tid] + wred[1][tid] + wred[2][tid] + wred[3][tid];
    const int dst = (tid == 0) ? 0 : (tid == 1) ? 1 : (tid == 2) ? 3 : 4;
    atomicAdd(&scal[dst], t);
  }
}

// logits + y + final loss in one launch (ecount now float in scal[4])
__global__ void logits_y_loss_k(const float* __restrict__ hc, const float* __restrict__ Wclf,
                                const float* __restrict__ bclf, const int* __restrict__ labels,
                                const float* __restrict__ scal,
                                float* __restrict__ outp) {
  const int i = blockIdx.x, f = threadIdx.x;  // 128 threads
  const float h = hc[(size_t)i * 128 + f];
  const float v0 = wave_sum(h * Wclf[f]);
  const float v1 = wave_sum(h * Wclf[128 + f]);
  __shared__ float w0[2], w1[2];
  if ((f & 63) == 0) { w0[f >> 6] = v0; w1[f >> 6] = v1; }
  __syncthreads();
  if (f == 0) {
    outp[(size_t)i * 2 + 0] = w0[0] + w0[1] + bclf[0];
    outp[(size_t)i * 2 + 1] = w1[0] + w1[1] + bclf[1];
    outp[12288 + i] = (i < 4096) ? (float)labels[i] : 1.f;
    if (i == 0) {
      const float cnt = scal[4];
      const float neg_w = cnt / (16777216.f - cnt);
      outp[18432] = neg_w * (scal[0] - scal[3]) + scal[1];
    }
  }
}

// ---------------- launcher ----------------
extern "C" void kernel_launch(void* const* d_in, const int* in_sizes, int n_in,
                              void* d_out, int out_size, void* d_ws, size_t ws_size,
                              hipStream_t stream) {
  const float* feat     = (const float*)d_in[0];
  const int*   src      = (const int*)d_in[2];
  const int*   dst      = (const int*)d_in[3];
  const int*   labels   = (const int*)d_in[4];
  const float* W_pool0  = (const float*)d_in[5];
  const float* b_pool0  = (const float*)d_in[6];
  const float* W_self0  = (const float*)d_in[7];
  const float* W_neigh0 = (const float*)d_in[8];
  const float* b0       = (const float*)d_in[9];
  const float* W_pool1  = (const float*)d_in[10];
  const float* b_pool1  = (const float*)d_in[11];
  const float* W_self1  = (const float*)d_in[12];
  const float* W_neigh1 = (const float*)d_in[13];
  const float* b1       = (const float*)d_in[14];
  const float* de_w     = (const float*)d_in[15];
  const float* W_conv   = (const float*)d_in[16];
  const float* W_clf    = (const float*)d_in[17];
  const float* b_clf    = (const float*)d_in[18];
  const float* gaps     = (const float*)d_in[19];
  const int E = in_sizes[2];  // 69632 (E + self-loops)

  float* ws = (float*)d_ws;
  float* p0       = ws + WS_P0;
  float* dots     = ws + WS_DOTS;
  ushort_t* obk   = (ushort_t*)(ws + WS_OBK);
  float* hn0      = ws + WS_HN0;
  unsigned* bitmap= (unsigned*)(ws + WS_BITMAP);
  float* hc       = ws + WS_HC;
  float* h1       = ws + WS_H1;
  float* h1n      = ws + WS_H1N;
  float* p1       = ws + WS_P1;
  ushort_t* pvb   = (ushort_t*)(ws + WS_PVB);
  float* hn1      = ws + WS_HN1;
  float* h2       = ws + WS_H2;
  float* synth    = ws + WS_X;
  float* neigh    = ws + WS_NEIGH;
  float* rowsum   = ws + WS_ROWSUM;
  float* scal     = ws + WS_SCAL;
  int* deg        = (int*)(ws + WS_DEG);
  int* nn         = (int*)(ws + WS_NN);
  int* cursor     = (int*)(ws + WS_CUR);
  int* rowptr     = (int*)(ws + WS_ROWPTR);
  int* eidx       = (int*)(ws + WS_EIDX);

  float* outp = (float*)d_out;
  const dim3 blk(256);

  // one contiguous zero region: neigh + rowsum + scal + deg
  hipMemsetAsync(neigh, 0, (size_t)(WS_DEG + 4096 - WS_NEIGH) * 4, stream);

  // CSR bucket-by-dst
  count_k<<<(E + 255) / 256, blk, 0, stream>>>(dst, deg, E);
  scan_k<<<1, 1024, 0, stream>>>(deg, rowptr, cursor);
  fill_k<<<(E + 255) / 256, blk, 0, stream>>>(src, dst, cursor, eidx, E);

  // layer 0
  gemm_nt<<<dim3(4, 64), blk, 0, stream>>>(feat, 256, W_pool0, 256,
                                           nullptr, 0, nullptr, 0,
                                           b_pool0, p0, 256, 256, 1, nullptr, nullptr, nullptr);
  segmax_k<<<4096, 256, 0, stream>>>(p0, rowptr, eidx, hn0, 256);
  gemm_nt<<<dim3(2, 64), blk, 0, stream>>>(feat, 256, W_self0, 256,
                                           hn0, 256, W_neigh0, 256,
                                           b0, h1, 128, 256, 0, nullptr, nullptr, nullptr);
  // relu+l2norm; also zeroes the bitmap (hn0 region is dead from here)
  relu_l2norm_k<<<4096, 128, 0, stream>>>(h1, h1n, bitmap);
  bitmap_build_k<<<(E + 255) / 256, blk, 0, stream>>>(src, dst, bitmap, E);

  // layer 1
  gemm_nt<<<dim3(2, 64), blk, 0, stream>>>(h1n, 128, W_pool1, 128,
                                           nullptr, 0, nullptr, 0,
                                           b_pool1, p1, 128, 128, 1, nullptr, nullptr, nullptr);
  segmax_k<<<4096, 128, 0, stream>>>(p1, rowptr, eidx, hn1, 128);
  gemm_nt<<<dim3(2, 64), blk, 0, stream>>>(h1n, 128, W_self1, 128,
                                           hn1, 128, W_neigh1, 128,
                                           b1, h2, 128, 128, 0, nullptr, nullptr, nullptr);

  // SMOTE: dots gemm (diag doubles as sqn), argmin, synth+pvb pack
  gemm_nt<<<dim3(16, 16), blk, 0, stream>>>(h2, 128, h2, 128,
                                            nullptr, 0, nullptr, 0,
                                            nullptr, dots, 1024, 128, 0, nullptr, nullptr, nullptr);
  argmin_k<<<1024, 256, 0, stream>>>(dots, nn);
  build_pack_k<<<192, blk, 0, stream>>>(h2, nn, gaps, synth, pvb);

  // decoder gemm writes obk-packed bf16 directly (dots dead -> obk region ok)
  gemm_nt<<<dim3(2, 96), blk, 0, stream>>>(h2, 128, de_w, 128,
                                           nullptr, 0, nullptr, 0,
                                           nullptr, nullptr, 0, 128, 0, obk, nullptr, synth);
  // dense fused pass: S_all/s1/sub/ecount + thresholded P@x + rowsum
  fused_mfma<<<dim3(192, 4), blk, 0, stream>>>(obk, pvb, bitmap, neigh, rowsum, scal);

  // classifier: neigh/(rowsum+1) folded into the gemm's A2 path
  gemm_nt<<<dim3(2, 96), blk, 0, stream>>>(h2, 128, W_conv, 256,
                                           neigh, 128, W_conv + 128, 256,
                                           nullptr, hc, 128, 128, 0, nullptr, rowsum, synth);
  logits_y_loss_k<<<6144, 128, 0, stream>>>(hc, W_clf, b_clf, labels, scal, outp);

  (void)n_in; (void)out_size; (void)ws_size; (void)in_sizes;
}

// Round 8
// 339.505 us; speedup vs baseline: 1.6112x; 1.1893x over previous
//
#include <hip/hip_runtime.h>
#include <cstddef>

typedef unsigned short ushort_t;
typedef __attribute__((ext_vector_type(8))) short bf16x8;
typedef __attribute__((ext_vector_type(4))) float f32x4;
typedef __attribute__((ext_vector_type(16))) float f32x16;

// ---------------- workspace layout (float offsets) ----------------
// [0..1048576): p0 (4096x256) -> dots (1024x1024); obk (packed bf16 6144x128 =
//               393216 f) at +524288 once dots is dead (after argmin).
#define WS_P0     0u
#define WS_DOTS   0u
#define WS_OBK    524288u
#define WS_HN0    1048576u   /* 4096x256; -> bitmap (524288 words) after h1 gemm; -> hc after fused */
#define WS_BITMAP 1048576u
#define WS_HC     1048576u
#define WS_H1     2097152u   /* 4096x128 */
#define WS_H1N    2621440u   /* 4096x128 */
#define WS_P1     3145728u   /* 4096x128; -> pvb (bf16 packed 192 tiles = 393216 f) */
#define WS_PVB    3145728u
#define WS_HN1    3670016u   /* 4096x128 */
#define WS_H2     4194304u   /* 4096x128 (live to the end now) */
#define WS_X      4718592u   /* synth 2048x128 (rows >= 4096 of x) */
#define WS_OB     5505024u   /* (unused now) */
// ---- contiguous zero region (one memset): ----
#define WS_NEIGH  6291456u   /* 786432 */
#define WS_ROWSUM 7077888u   /* 6144 */
#define WS_SCAL   7084032u   /* 16 floats: [S_all, s1, -, sub, ecount_f] */
#define WS_DEG    7084048u   /* int 4096 */
// ---- end zero region ----
#define WS_NN     7088144u   /* int 1024 */
#define WS_CUR    7089168u   /* int 4096 */
#define WS_ROWPTR 7093264u   /* int 4097 */
#define WS_EIDX   7097361u   /* int 69632 */

__device__ inline ushort_t f2bf(float f) {
  unsigned u = __float_as_uint(f);
  u += 0x7fff + ((u >> 16) & 1);   // round-to-nearest-even
  return (ushort_t)(u >> 16);
}

// ---------------- generic NT GEMM: C = act(A@B^T (+ A2@B2^T) + bias) -------
// Ahi: optional second A base for rows >= 4096 (split h2/synth, block-uniform).
// Cb: when set, write bf16 output in the obk-packed fragment layout.
__global__ __launch_bounds__(256, 2) void gemm_nt(
    const float* __restrict__ A, int lda,
    const float* __restrict__ B, int ldb,
    const float* __restrict__ A2, int lda2,
    const float* __restrict__ B2, int ldb2,
    const float* __restrict__ bias,
    float* __restrict__ C, int ldc,
    int K, int relu,
    ushort_t* __restrict__ Cb,
    const float* __restrict__ a2scale,
    const float* __restrict__ Ahi)
{
  __shared__ float As[16][68];
  __shared__ float Bs[16][68];
  const int tid = threadIdx.x;
  const int tx = tid & 15, ty = tid >> 4;
  const int lr = tid >> 2;
  const int lk = (tid & 3) << 2;
  const int i0 = blockIdx.y << 6;
  const int j0 = blockIdx.x << 6;
  float acc[4][4] = {};
  const int npass = (A2 != nullptr) ? 2 : 1;
  for (int pass = 0; pass < npass; ++pass) {
    const float* Ap = pass ? A2 : A; const int la = pass ? lda2 : lda;
    const float* Bp = pass ? B2 : B; const int lb = pass ? ldb2 : ldb;
    const float sc = (pass && a2scale) ? __frcp_rn(a2scale[i0 + lr] + 1.f) : 1.f;
    const float* Arow = (pass == 0 && Ahi != nullptr && i0 >= 4096)
        ? (Ahi + (size_t)(i0 - 4096 + lr) * la)
        : (Ap + (size_t)(i0 + lr) * la);
    for (int k0 = 0; k0 < K; k0 += 16) {
      float4 ag = *(const float4*)(Arow + (k0 + lk));
      const float4 bg = *(const float4*)(Bp + (size_t)(j0 + lr) * lb + (k0 + lk));
      ag.x *= sc; ag.y *= sc; ag.z *= sc; ag.w *= sc;
      __syncthreads();
      As[lk+0][lr]=ag.x; As[lk+1][lr]=ag.y; As[lk+2][lr]=ag.z; As[lk+3][lr]=ag.w;
      Bs[lk+0][lr]=bg.x; Bs[lk+1][lr]=bg.y; Bs[lk+2][lr]=bg.z; Bs[lk+3][lr]=bg.w;
      __syncthreads();
#pragma unroll
      for (int k = 0; k < 16; ++k) {
        const float4 a4 = *(const float4*)&As[k][ty << 2];
        const float4 b4 = *(const float4*)&Bs[k][tx << 2];
        const float aa[4] = {a4.x, a4.y, a4.z, a4.w};
        const float bb[4] = {b4.x, b4.y, b4.z, b4.w};
#pragma unroll
        for (int ii = 0; ii < 4; ++ii)
#pragma unroll
          for (int jj = 0; jj < 4; ++jj)
            acc[ii][jj] += aa[ii] * bb[jj];
      }
    }
  }
  float badd[4] = {0.f, 0.f, 0.f, 0.f};
  if (bias) {
    const float4 t = *(const float4*)(bias + j0 + (tx << 2));
    badd[0]=t.x; badd[1]=t.y; badd[2]=t.z; badd[3]=t.w;
  }
#pragma unroll
  for (int ii = 0; ii < 4; ++ii) {
    float4 o;
    o.x = acc[ii][0] + badd[0];
    o.y = acc[ii][1] + badd[1];
    o.z = acc[ii][2] + badd[2];
    o.w = acc[ii][3] + badd[3];
    if (relu) { o.x=fmaxf(o.x,0.f); o.y=fmaxf(o.y,0.f); o.z=fmaxf(o.z,0.f); o.w=fmaxf(o.w,0.f); }
    if (Cb) {
      // obk-packed write: off(i,j) = (i>>5)<<12 | (j>>4)<<9 | (((j>>3)&1)<<5 | (i&31))<<3 | (j&7)
      const int i_ = i0 + (ty << 2) + ii;
      const int j_ = j0 + (tx << 2);
      const size_t off = ((size_t)(i_ >> 5) << 12) +
                         (size_t)(((j_ >> 4) << 9) +
                                  ((((( j_ >> 3) & 1) << 5) + (i_ & 31)) << 3) +
                                  (j_ & 7));
      ushort4 ob4;
      ob4.x = f2bf(o.x); ob4.y = f2bf(o.y); ob4.z = f2bf(o.z); ob4.w = f2bf(o.w);
      *(ushort4*)(Cb + off) = ob4;
    } else {
      const size_t off = (size_t)(i0 + (ty<<2) + ii) * ldc + j0 + (tx<<2);
      *(float4*)(C + off) = o;
    }
  }
}

// ---------------- CSR build (bucket edges by dst) ----------------
__global__ void count_k(const int* __restrict__ dst, int* __restrict__ deg, int E) {
  const int e = blockIdx.x * 256 + threadIdx.x;
  if (e < E) atomicAdd(&deg[dst[e]], 1);
}

__global__ __launch_bounds__(1024) void scan_k(const int* __restrict__ deg,
                                               int* __restrict__ rowptr,
                                               int* __restrict__ cursor) {
  __shared__ int sums[1024];
  const int t = threadIdx.x;
  const int4 d = *(const int4*)(deg + (t << 2));
  const int local = d.x + d.y + d.z + d.w;
  sums[t] = local;
  __syncthreads();
  for (int off = 1; off < 1024; off <<= 1) {
    int v = (t >= off) ? sums[t - off] : 0;
    __syncthreads();
    sums[t] += v;
    __syncthreads();
  }
  const int excl = sums[t] - local;
  const int o0 = excl, o1 = o0 + d.x, o2 = o1 + d.y, o3 = o2 + d.z;
  rowptr[(t<<2)+0]=o0; rowptr[(t<<2)+1]=o1; rowptr[(t<<2)+2]=o2; rowptr[(t<<2)+3]=o3;
  cursor[(t<<2)+0]=o0; cursor[(t<<2)+1]=o1; cursor[(t<<2)+2]=o2; cursor[(t<<2)+3]=o3;
  if (t == 1023) rowptr[4096] = sums[1023];
}

__global__ void fill_k(const int* __restrict__ src, const int* __restrict__ dst,
                       int* __restrict__ cursor, int* __restrict__ eidx, int E) {
  const int e = blockIdx.x * 256 + threadIdx.x;
  if (e < E) {
    const int p = atomicAdd(&cursor[dst[e]], 1);
    eidx[p] = src[e];
  }
}

// adjacency bitmap: bit(cell) for cell = dst*4096 + src (distinct via OR)
__global__ void bitmap_build_k(const int* __restrict__ src, const int* __restrict__ dst,
                               unsigned* __restrict__ bitmap, int E) {
  const int e = blockIdx.x * 256 + threadIdx.x;
  if (e < E) {
    const unsigned cell = ((unsigned)dst[e] << 12) + (unsigned)src[e];
    atomicOr(&bitmap[cell >> 5], 1u << (cell & 31));
  }
}

// segment_max as CSR gather. p >= 0 (relu'd) and every segment non-empty
// (self-loops), so init 0 reproduces the isfinite->0 semantics exactly.
__global__ void segmax_k(const float* __restrict__ p, const int* __restrict__ rowptr,
                         const int* __restrict__ eidx, float* __restrict__ hn, int F) {
  const int row = blockIdx.x, f = threadIdx.x;  // blockDim == F
  const int b = rowptr[row], e = rowptr[row + 1];
  float m = 0.f;
  for (int k = b; k < e; ++k) m = fmaxf(m, p[(size_t)eidx[k] * F + f]);
  hn[(size_t)row * F + f] = m;
}

// ---------------- small fused elementwise / reductions ----------------
__device__ inline float wave_sum(float v) {
#pragma unroll
  for (int o = 32; o > 0; o >>= 1) v += __shfl_down(v, o, 64);
  return v;
}

// relu + row l2norm; also zeroes the adjacency bitmap (1 word/thread exactly)
__global__ void relu_l2norm_k(const float* __restrict__ in, float* __restrict__ out,
                              unsigned* __restrict__ bitmap) {
  const int row = blockIdx.x, f = threadIdx.x;  // 128 threads, grid 4096
  bitmap[(blockIdx.x << 7) + f] = 0u;
  const float v = fmaxf(in[(size_t)row * 128 + f], 0.f);
  const float ss = wave_sum(v * v);
  __shared__ float w[2];
  if ((f & 63) == 0) w[f >> 6] = ss;
  __syncthreads();
  const float denom = fmaxf(sqrtf(w[0] + w[1]), 1e-12f);
  out[(size_t)row * 128 + f] = v / denom;
}

// nearest neighbor (excluding self); sqn comes from the diag of dots
__global__ void argmin_k(const float* __restrict__ dots, int* __restrict__ nn) {
  __shared__ float sqd[1024];
  const int i = blockIdx.x, tid = threadIdx.x;  // 256 threads
#pragma unroll
  for (int z = 0; z < 4; ++z) {
    const int j = (tid << 2) + z;
    sqd[j] = dots[(size_t)j * 1025];   // dots[j][j]
  }
  __syncthreads();
  float best = 3.402823466e38f; int bidx = 0x7fffffff;
  const float si = sqd[i];
  for (int j = tid; j < 1024; j += 256) {
    if (j == i) continue;
    float d2 = si + sqd[j] - 2.f * dots[(size_t)i * 1024 + j];
    d2 = fmaxf(d2, 0.f);
    if (d2 < best || (d2 == best && j < bidx)) { best = d2; bidx = j; }
  }
  __shared__ float bv[256]; __shared__ int bi[256];
  bv[tid] = best; bi[tid] = bidx;
  __syncthreads();
  for (int s = 128; s > 0; s >>= 1) {
    if (tid < s) {
      if (bv[tid+s] < bv[tid] || (bv[tid+s] == bv[tid] && bi[tid+s] < bi[tid])) {
        bv[tid] = bv[tid+s]; bi[tid] = bi[tid+s];
      }
    }
    __syncthreads();
  }
  if (tid == 0) nn[i] = bi[0];
}

// build synth rows (SMOTE interp) AND pack pvb fragments in one pass.
// grid 192 (one 32-row j-tile each); jt<128 sources h2, else computes synth
// (also materializing the f32 synth rows for the downstream gemms' A-operand).
__global__ __launch_bounds__(256) void build_pack_k(
    const float* __restrict__ h2, const int* __restrict__ nn,
    const float* __restrict__ gaps, float* __restrict__ synth,
    ushort_t* __restrict__ pvb) {
  __shared__ ushort_t s[4096];  // [32 j][128 f] bf16
  const int jt = blockIdx.x, tid = threadIdx.x;
  if (jt < 128) {
    const float* ip = h2 + ((size_t)jt << 12);
#pragma unroll
    for (int k = 0; k < 4; ++k) {
      const float4 v = *(const float4*)(ip + (tid << 4) + (k << 2));
      ushort4 h; h.x = f2bf(v.x); h.y = f2bf(v.y); h.z = f2bf(v.z); h.w = f2bf(v.w);
      *(ushort4*)(s + (tid << 4) + (k << 2)) = h;
    }
  } else {
    const int row = tid >> 3;                       // 0..31
    const int sIdx = ((jt - 128) << 5) + row;       // synth row (= 2i+rep)
    const int i = sIdx >> 1;
    const float g = gaps[sIdx];
    const int ni = nn[i];
#pragma unroll
    for (int k = 0; k < 4; ++k) {
      const int f = ((tid & 7) << 4) + (k << 2);
      const float4 c4 = *(const float4*)(h2 + (size_t)i * 128 + f);
      const float4 n4 = *(const float4*)(h2 + (size_t)ni * 128 + f);
      float4 v;
      v.x = c4.x + g * (n4.x - c4.x);
      v.y = c4.y + g * (n4.y - c4.y);
      v.z = c4.z + g * (n4.z - c4.z);
      v.w = c4.w + g * (n4.w - c4.w);
      *(float4*)(synth + (size_t)sIdx * 128 + f) = v;
      ushort4 h; h.x = f2bf(v.x); h.y = f2bf(v.y); h.z = f2bf(v.z); h.w = f2bf(v.w);
      *(ushort4*)(s + (row << 7) + f) = h;
    }
  }
  __syncthreads();
  const int u = tid & 31, ft = (tid >> 5) & 3, cc = tid >> 7;
  ushort_t* op = pvb + ((size_t)jt << 12) + (cc << 11) + (ft << 9);
#pragma unroll
  for (int m = 0; m < 2; ++m) {
    const int l = (u << 1) + m;
    const int f = (ft << 5) + (l & 31);
    const int jb = (cc << 4) + ((l >> 5) << 3);
    ushort4 o0, o1;
    o0.x = s[(jb + 0) * 128 + f]; o0.y = s[(jb + 1) * 128 + f];
    o0.z = s[(jb + 2) * 128 + f]; o0.w = s[(jb + 3) * 128 + f];
    o1.x = s[(jb + 4) * 128 + f]; o1.y = s[(jb + 5) * 128 + f];
    o1.z = s[(jb + 6) * 128 + f]; o1.w = s[(jb + 7) * 128 + f];
    *(ushort4*)(op + (l << 3) + 0) = o0;
    *(ushort4*)(op + (l << 3) + 4) = o1;
  }
}

// ---------------- fused MFMA v9: v5 decomposition + in-kernel edge loss ----
// Post-mortem r7: v8's grid change un-shared the j-streams (4 waves = 4
// different j-tiles -> 4x unique L1 traffic) and ran 1.5 scheduling rounds
// (768 blocks @ 2/CU) -> 2x slower than v5's 64us at identical tile-work.
// v9 restores v5 exactly: grid (48,12), wave owns i-tile bx*4+w, ALL waves
// share the j-stream (L1 reuse), direct atomic flush (proven free), tiny LDS.
// Only addition: the bitmap word load + loss accumulation from v8.
__global__ __launch_bounds__(256, 2) void fused_mfma(
    const ushort_t* __restrict__ obk,  // packed A/Q frags [192][8][64][8]
    const ushort_t* __restrict__ pvb,  // packed PV B frags [192][2][4][64][8]
    const unsigned* __restrict__ bitmap,
    float* __restrict__ neigh,         // 6144x128, pre-zeroed
    float* __restrict__ rowsum,        // 6144, pre-zeroed
    float* __restrict__ scal)          // [S_all, s1, -, sub, ecnt], pre-zeroed
{
  __shared__ float wred[4][4];
  const int tid = threadIdx.x;
  const int w = tid >> 6;
  const int lane = tid & 63;
  const int lo = lane & 31, hi = lane >> 5;
  const int it = (blockIdx.x << 2) + w;  // wave's i-tile (32 rows)
  const int iw = it << 5;
  const int jt0 = blockIdx.y << 4;       // shared j-strip: 16 tiles
  const bool loss_i = (it < 128);        // i < 4096 (wave-uniform)

  // Q-frags (B operand of S^T), persistent: coalesced 16B/lane loads
  bf16x8 qf[8];
  {
    const ushort_t* qp = obk + ((size_t)it << 12) + (lane << 3);
#pragma unroll
    for (int c = 0; c < 8; ++c) qf[c] = *(const bf16x8*)(qp + (c << 9));
  }
  f32x16 oacc[4];
#pragma unroll
  for (int ft = 0; ft < 4; ++ft)
#pragma unroll
    for (int r = 0; r < 16; ++r) oacc[ft][r] = 0.f;
  float rs = 0.f, s_all = 0.f, s1a = 0.f, suba = 0.f, ecf = 0.f;

  // K-frags (A operand) for tile 0 — shared addresses across the 4 waves
  bf16x8 a[8];
  {
    const ushort_t* kp = obk + ((size_t)jt0 << 12) + (lane << 3);
#pragma unroll
    for (int c = 0; c < 8; ++c) a[c] = *(const bf16x8*)(kp + (c << 9));
  }

  for (int t = 0; t < 16; ++t) {
    const int jt = jt0 + t;
    // S^T: two 4-deep accumulator chains (a already in regs)
    f32x16 s0, s1;
#pragma unroll
    for (int r = 0; r < 16; ++r) { s0[r] = 0.f; s1[r] = 0.f; }
#pragma unroll
    for (int c = 0; c < 4; ++c) {
      s0 = __builtin_amdgcn_mfma_f32_32x32x16_bf16(a[c], qf[c], s0, 0, 0, 0);
      s1 = __builtin_amdgcn_mfma_f32_32x32x16_bf16(a[c + 4], qf[c + 4], s1, 0, 0, 0);
    }
    // PV B-frags for THIS tile (consumed after sigmoid)
    bf16x8 bvf[2][4];
    {
      const ushort_t* vp = pvb + ((size_t)jt << 12) + (lane << 3);
#pragma unroll
      for (int cc = 0; cc < 2; ++cc)
#pragma unroll
        for (int ft = 0; ft < 4; ++ft)
          bvf[cc][ft] = *(const bf16x8*)(vp + (cc << 11) + (ft << 9));
    }
    // prefetch next tile's K-frags (latency under sigmoid+PV)
    if (t < 15) {
      const ushort_t* kp = obk + ((size_t)(jt + 1) << 12) + (lane << 3);
#pragma unroll
      for (int c = 0; c < 8; ++c) a[c] = *(const bf16x8*)(kp + (c << 9));
    }
    // adjacency word for this lane's i-row (loss region only; indep load)
    const bool loss_t = loss_i && (jt < 128);
    unsigned word = 0u;
    if (loss_t) word = bitmap[((unsigned)(iw + lo) << 7) + (unsigned)jt];
    // sigmoid + threshold + rowsum + loss terms
    float p[16];
    if (loss_t) {
      ecf += (float)__popc(word & (0x0F0F0F0Fu << (hi << 2)));
#pragma unroll
      for (int r = 0; r < 16; ++r) {
        const float v = s0[r] + s1[r];
        const float sg = __builtin_amdgcn_rcpf(1.f + __expf(-v));
        const int jl = (r & 3) + ((r >> 2) << 3) + (hi << 2);
        const float e_ = (float)((word >> jl) & 1u);
        s_all += sg * sg;
        s1a  += e_ * (sg - 1.f) * (sg - 1.f);
        suba += e_ * sg * sg;
        const float tv = (v >= 0.f) ? sg : 0.f;   // sg>=0.5 <=> v>=0
        p[r] = tv; rs += tv;
      }
    } else {
#pragma unroll
      for (int r = 0; r < 16; ++r) {
        const float v = s0[r] + s1[r];
        const float sg = __builtin_amdgcn_rcpf(1.f + __expf(-v));
        const float tv = (v >= 0.f) ? sg : 0.f;
        p[r] = tv; rs += tv;
      }
    }
    // pack P -> bf16 PV A-frags: cvt_pk pairs + permlane32_swap (T12)
#pragma unroll
    for (int cc = 0; cc < 2; ++cc) {
      const int b8 = cc << 3;
      unsigned c01, c23, c45, c67;
      asm("v_cvt_pk_bf16_f32 %0, %1, %2" : "=v"(c01) : "v"(p[b8+0]), "v"(p[b8+1]));
      asm("v_cvt_pk_bf16_f32 %0, %1, %2" : "=v"(c23) : "v"(p[b8+2]), "v"(p[b8+3]));
      asm("v_cvt_pk_bf16_f32 %0, %1, %2" : "=v"(c45) : "v"(p[b8+4]), "v"(p[b8+5]));
      asm("v_cvt_pk_bf16_f32 %0, %1, %2" : "=v"(c67) : "v"(p[b8+6]), "v"(p[b8+7]));
      const auto w0 = __builtin_amdgcn_permlane32_swap((int)c01, (int)c45, false, false);
      const auto w1 = __builtin_amdgcn_permlane32_swap((int)c23, (int)c67, false, false);
      union { int i[4]; bf16x8 h; } u;
      u.i[0] = w0[0]; u.i[1] = w1[0]; u.i[2] = w0[1]; u.i[3] = w1[1];
#pragma unroll
      for (int ft = 0; ft < 4; ++ft)
        oacc[ft] = __builtin_amdgcn_mfma_f32_32x32x16_bf16(u.h, bvf[cc][ft], oacc[ft], 0, 0, 0);
    }
  }
  // ---- neigh flush: direct atomics (12-way across j-strips; proven cheap) --
#pragma unroll
  for (int ft = 0; ft < 4; ++ft)
#pragma unroll
    for (int r = 0; r < 16; ++r) {
      const int ir = (r & 3) + ((r >> 2) << 3) + (hi << 2);
      atomicAdd(&neigh[(size_t)(iw + ir) * 128 + (ft << 5) + lo], oacc[ft][r]);
    }
  // ---- rowsum: lane pair (hi=0,1) shares i = iw+lo ----
  rs += __shfl_xor(rs, 32, 64);
  if (hi == 0) atomicAdd(&rowsum[iw + lo], rs);
  // ---- scalar partials: wave-reduce, stash per wave, one barrier ----
  {
    float v0 = wave_sum(s_all), v1 = wave_sum(s1a), v2 = wave_sum(suba), v3 = wave_sum(ecf);
    if (lane == 0) { wred[w][0] = v0; wred[w][1] = v1; wred[w][2] = v2; wred[w][3] = v3; }
  }
  __syncthreads();
  if (tid < 4) {
    const float t = wred[0][tid] + wred[1][tid] + wred[2][tid] + wred[3][tid];
    const int dst = (tid == 0) ? 0 : (tid == 1) ? 1 : (tid == 2) ? 3 : 4;
    atomicAdd(&scal[dst], t);
  }
}

// logits + y + final loss in one launch (ecount now float in scal[4])
__global__ void logits_y_loss_k(const float* __restrict__ hc, const float* __restrict__ Wclf,
                                const float* __restrict__ bclf, const int* __restrict__ labels,
                                const float* __restrict__ scal,
                                float* __restrict__ outp) {
  const int i = blockIdx.x, f = threadIdx.x;  // 128 threads
  const float h = hc[(size_t)i * 128 + f];
  const float v0 = wave_sum(h * Wclf[f]);
  const float v1 = wave_sum(h * Wclf[128 + f]);
  __shared__ float w0[2], w1[2];
  if ((f & 63) == 0) { w0[f >> 6] = v0; w1[f >> 6] = v1; }
  __syncthreads();
  if (f == 0) {
    outp[(size_t)i * 2 + 0] = w0[0] + w0[1] + bclf[0];
    outp[(size_t)i * 2 + 1] = w1[0] + w1[1] + bclf[1];
    outp[12288 + i] = (i < 4096) ? (float)labels[i] : 1.f;
    if (i == 0) {
      const float cnt = scal[4];
      const float neg_w = cnt / (16777216.f - cnt);
      outp[18432] = neg_w * (scal[0] - scal[3]) + scal[1];
    }
  }
}

// ---------------- launcher ----------------
extern "C" void kernel_launch(void* const* d_in, const int* in_sizes, int n_in,
                              void* d_out, int out_size, void* d_ws, size_t ws_size,
                              hipStream_t stream) {
  const float* feat     = (const float*)d_in[0];
  const int*   src      = (const int*)d_in[2];
  const int*   dst      = (const int*)d_in[3];
  const int*   labels   = (const int*)d_in[4];
  const float* W_pool0  = (const float*)d_in[5];
  const float* b_pool0  = (const float*)d_in[6];
  const float* W_self0  = (const float*)d_in[7];
  const float* W_neigh0 = (const float*)d_in[8];
  const float* b0       = (const float*)d_in[9];
  const float* W_pool1  = (const float*)d_in[10];
  const float* b_pool1  = (const float*)d_in[11];
  const float* W_self1  = (const float*)d_in[12];
  const float* W_neigh1 = (const float*)d_in[13];
  const float* b1       = (const float*)d_in[14];
  const float* de_w     = (const float*)d_in[15];
  const float* W_conv   = (const float*)d_in[16];
  const float* W_clf    = (const float*)d_in[17];
  const float* b_clf    = (const float*)d_in[18];
  const float* gaps     = (const float*)d_in[19];
  const int E = in_sizes[2];  // 69632 (E + self-loops)

  float* ws = (float*)d_ws;
  float* p0       = ws + WS_P0;
  float* dots     = ws + WS_DOTS;
  ushort_t* obk   = (ushort_t*)(ws + WS_OBK);
  float* hn0      = ws + WS_HN0;
  unsigned* bitmap= (unsigned*)(ws + WS_BITMAP);
  float* hc       = ws + WS_HC;
  float* h1       = ws + WS_H1;
  float* h1n      = ws + WS_H1N;
  float* p1       = ws + WS_P1;
  ushort_t* pvb   = (ushort_t*)(ws + WS_PVB);
  float* hn1      = ws + WS_HN1;
  float* h2       = ws + WS_H2;
  float* synth    = ws + WS_X;
  float* neigh    = ws + WS_NEIGH;
  float* rowsum   = ws + WS_ROWSUM;
  float* scal     = ws + WS_SCAL;
  int* deg        = (int*)(ws + WS_DEG);
  int* nn         = (int*)(ws + WS_NN);
  int* cursor     = (int*)(ws + WS_CUR);
  int* rowptr     = (int*)(ws + WS_ROWPTR);
  int* eidx       = (int*)(ws + WS_EIDX);

  float* outp = (float*)d_out;
  const dim3 blk(256);

  // one contiguous zero region: neigh + rowsum + scal + deg
  hipMemsetAsync(neigh, 0, (size_t)(WS_DEG + 4096 - WS_NEIGH) * 4, stream);

  // CSR bucket-by-dst
  count_k<<<(E + 255) / 256, blk, 0, stream>>>(dst, deg, E);
  scan_k<<<1, 1024, 0, stream>>>(deg, rowptr, cursor);
  fill_k<<<(E + 255) / 256, blk, 0, stream>>>(src, dst, cursor, eidx, E);

  // layer 0
  gemm_nt<<<dim3(4, 64), blk, 0, stream>>>(feat, 256, W_pool0, 256,
                                           nullptr, 0, nullptr, 0,
                                           b_pool0, p0, 256, 256, 1, nullptr, nullptr, nullptr);
  segmax_k<<<4096, 256, 0, stream>>>(p0, rowptr, eidx, hn0, 256);
  gemm_nt<<<dim3(2, 64), blk, 0, stream>>>(feat, 256, W_self0, 256,
                                           hn0, 256, W_neigh0, 256,
                                           b0, h1, 128, 256, 0, nullptr, nullptr, nullptr);
  // relu+l2norm; also zeroes the bitmap (hn0 region is dead from here)
  relu_l2norm_k<<<4096, 128, 0, stream>>>(h1, h1n, bitmap);
  bitmap_build_k<<<(E + 255) / 256, blk, 0, stream>>>(src, dst, bitmap, E);

  // layer 1
  gemm_nt<<<dim3(2, 64), blk, 0, stream>>>(h1n, 128, W_pool1, 128,
                                           nullptr, 0, nullptr, 0,
                                           b_pool1, p1, 128, 128, 1, nullptr, nullptr, nullptr);
  segmax_k<<<4096, 128, 0, stream>>>(p1, rowptr, eidx, hn1, 128);
  gemm_nt<<<dim3(2, 64), blk, 0, stream>>>(h1n, 128, W_self1, 128,
                                           hn1, 128, W_neigh1, 128,
                                           b1, h2, 128, 128, 0, nullptr, nullptr, nullptr);

  // SMOTE: dots gemm (diag doubles as sqn), argmin, synth+pvb pack
  gemm_nt<<<dim3(16, 16), blk, 0, stream>>>(h2, 128, h2, 128,
                                            nullptr, 0, nullptr, 0,
                                            nullptr, dots, 1024, 128, 0, nullptr, nullptr, nullptr);
  argmin_k<<<1024, 256, 0, stream>>>(dots, nn);
  build_pack_k<<<192, blk, 0, stream>>>(h2, nn, gaps, synth, pvb);

  // decoder gemm writes obk-packed bf16 directly (dots dead -> obk region ok)
  gemm_nt<<<dim3(2, 96), blk, 0, stream>>>(h2, 128, de_w, 128,
                                           nullptr, 0, nullptr, 0,
                                           nullptr, nullptr, 0, 128, 0, obk, nullptr, synth);
  // dense fused pass: S_all/s1/sub/ecount + thresholded P@x + rowsum
  fused_mfma<<<dim3(48, 12), blk, 0, stream>>>(obk, pvb, bitmap, neigh, rowsum, scal);

  // classifier: neigh/(rowsum+1) folded into the gemm's A2 path
  gemm_nt<<<dim3(2, 96), blk, 0, stream>>>(h2, 128, W_conv, 256,
                                           neigh, 128, W_conv + 128, 256,
                                           nullptr, hc, 128, 128, 0, nullptr, rowsum, synth);
  logits_y_loss_k<<<6144, 128, 0, stream>>>(hc, W_clf, b_clf, labels, scal, outp);

  (void)n_in; (void)out_size; (void)ws_size; (void)in_sizes;
}